// Round 2
// 476.846 us; speedup vs baseline: 1.0055x; 1.0055x over previous
//
#include <hip/hip_runtime.h>
#include <math.h>

#define EPS 1e-5

constexpr int B = 32, C = 64, H = 128, W = 128;
constexpr int HW = H * W;                  // 16384 pairs per (b,c) plane
constexpr int NSAMP = B * HW;              // 524288 samples per channel
constexpr int PLANE_FLOATS = HW * 2;       // 32768 floats per plane
constexpr int PLANE_F4 = PLANE_FLOATS / 4; // 8192 float4 per plane
constexpr int PLANES = B * C;              // 2048

typedef float vfloat4 __attribute__((ext_vector_type(4)));

// Pass 1: per-plane partial sums -> ws[blk*8 + 0..4], plain stores (no atomics,
// no memset needed). 4 independent load chains for memory-level parallelism.
__global__ __launch_bounds__(256) void reduce_kernel(const float* __restrict__ z,
                                                     float* __restrict__ ws) {
    const int blk = blockIdx.x;          // b*C + c
    const vfloat4* p = (const vfloat4*)(z + (size_t)blk * PLANE_FLOATS);

    float s0 = 0.f, s1 = 0.f, s00 = 0.f, s01 = 0.f, s11 = 0.f;
    for (int base = 0; base < PLANE_F4; base += 1024) {
        const int i = base + threadIdx.x;
        vfloat4 v0 = p[i];
        vfloat4 v1 = p[i + 256];
        vfloat4 v2 = p[i + 512];
        vfloat4 v3 = p[i + 768];
        s0  += (v0.x + v0.z) + (v1.x + v1.z) + (v2.x + v2.z) + (v3.x + v3.z);
        s1  += (v0.y + v0.w) + (v1.y + v1.w) + (v2.y + v2.w) + (v3.y + v3.w);
        s00 += (v0.x * v0.x + v0.z * v0.z) + (v1.x * v1.x + v1.z * v1.z)
             + (v2.x * v2.x + v2.z * v2.z) + (v3.x * v3.x + v3.z * v3.z);
        s11 += (v0.y * v0.y + v0.w * v0.w) + (v1.y * v1.y + v1.w * v1.w)
             + (v2.y * v2.y + v2.w * v2.w) + (v3.y * v3.y + v3.w * v3.w);
        s01 += (v0.x * v0.y + v0.z * v0.w) + (v1.x * v1.y + v1.z * v1.w)
             + (v2.x * v2.y + v2.z * v2.w) + (v3.x * v3.y + v3.z * v3.w);
    }

    #pragma unroll
    for (int o = 32; o > 0; o >>= 1) {
        s0  += __shfl_down(s0,  o, 64);
        s1  += __shfl_down(s1,  o, 64);
        s00 += __shfl_down(s00, o, 64);
        s01 += __shfl_down(s01, o, 64);
        s11 += __shfl_down(s11, o, 64);
    }

    __shared__ float sm[5][4];
    const int lane = threadIdx.x & 63;
    const int wv = threadIdx.x >> 6;
    if (lane == 0) {
        sm[0][wv] = s0; sm[1][wv] = s1; sm[2][wv] = s00; sm[3][wv] = s01; sm[4][wv] = s11;
    }
    __syncthreads();
    if (threadIdx.x == 0) {
        float t0 = 0.f, t1 = 0.f, t2 = 0.f, t3 = 0.f, t4 = 0.f;
        #pragma unroll
        for (int w = 0; w < 4; w++) {
            t0 += sm[0][w]; t1 += sm[1][w]; t2 += sm[2][w]; t3 += sm[3][w]; t4 += sm[4][w];
        }
        float* wp = ws + (size_t)blk * 8;
        wp[0] = t0; wp[1] = t1; wp[2] = t2; wp[3] = t3; wp[4] = t4;
    }
}

// Pass 2: wave 0 reduces the channel's 32 per-plane partials (L2-resident),
// one thread derives the 2x2 affine in double, broadcast via LDS, then apply.
// Traversal is REVERSED vs pass 1 so the freshest L3 lines are consumed first.
__global__ __launch_bounds__(256) void apply_kernel(const float* __restrict__ z,
                                                    const float* __restrict__ ws,
                                                    const float* __restrict__ gamma,
                                                    const float* __restrict__ beta,
                                                    float* __restrict__ out) {
    const int blk = blockIdx.x;          // b*C + c
    const int c = blk & (C - 1);

    __shared__ float tr[6];              // A00, A01, A10, A11, b0, b1
    if (threadIdx.x < 64) {
        float a0 = 0.f, a1 = 0.f, a2 = 0.f, a3 = 0.f, a4 = 0.f;
        if (threadIdx.x < B) {           // 32 partials per channel
            const float* wp = ws + (size_t)(threadIdx.x * C + c) * 8;
            a0 = wp[0]; a1 = wp[1]; a2 = wp[2]; a3 = wp[3]; a4 = wp[4];
        }
        #pragma unroll
        for (int o = 16; o > 0; o >>= 1) {
            a0 += __shfl_down(a0, o, 64);
            a1 += __shfl_down(a1, o, 64);
            a2 += __shfl_down(a2, o, 64);
            a3 += __shfl_down(a3, o, 64);
            a4 += __shfl_down(a4, o, 64);
        }
        if (threadIdx.x == 0) {
            const double S0 = a0, S1 = a1, S00 = a2, S01 = a3, S11 = a4;
            const double invN = 1.0 / (double)NSAMP;
            const double mu0 = S0 * invN, mu1 = S1 * invN;
            const double va = S00 * invN - mu0 * mu0 + EPS;
            const double vb = S01 * invN - mu0 * mu1;
            const double vd = S11 * invN - mu1 * mu1 + EPS;
            const double sdet = sqrt(va * vd - vb * vb);
            const double tt = sqrt(va + vd + 2.0 * sdet);
            const double sa = (va + sdet) / tt;
            const double sb = vb / tt;
            const double sd2 = (vd + sdet) / tt;
            const double inv_det = 1.0 / (sa * sd2 - sb * sb);
            const double w00 =  sd2 * inv_det;
            const double w01 = -sb  * inv_det;   // == w10 (symmetric)
            const double w11 =  sa  * inv_det;
            const double g00 = gamma[0], g01 = gamma[1], g10 = gamma[2], g11 = gamma[3];
            const double A00 = g00 * w00 + g01 * w01;
            const double A01 = g00 * w01 + g01 * w11;
            const double A10 = g10 * w00 + g11 * w01;
            const double A11 = g10 * w01 + g11 * w11;
            tr[0] = (float)A00; tr[1] = (float)A01; tr[2] = (float)A10; tr[3] = (float)A11;
            tr[4] = (float)((double)beta[0] - (A00 * mu0 + A01 * mu1));
            tr[5] = (float)((double)beta[1] - (A10 * mu0 + A11 * mu1));
        }
    }
    __syncthreads();
    const float A00 = tr[0], A01 = tr[1], A10 = tr[2], A11 = tr[3];
    const float b0 = tr[4], b1 = tr[5];

    const vfloat4* p = (const vfloat4*)(z + (size_t)blk * PLANE_FLOATS);
    vfloat4* q = (vfloat4*)(out + (size_t)blk * PLANE_FLOATS);
    for (int base = PLANE_F4 - 1024; base >= 0; base -= 1024) {
        const int i = base + threadIdx.x;
        vfloat4 v0 = p[i];
        vfloat4 v1 = p[i + 256];
        vfloat4 v2 = p[i + 512];
        vfloat4 v3 = p[i + 768];
        vfloat4 r0, r1, r2, r3;
        r0.x = A00 * v0.x + A01 * v0.y + b0;  r0.y = A10 * v0.x + A11 * v0.y + b1;
        r0.z = A00 * v0.z + A01 * v0.w + b0;  r0.w = A10 * v0.z + A11 * v0.w + b1;
        r1.x = A00 * v1.x + A01 * v1.y + b0;  r1.y = A10 * v1.x + A11 * v1.y + b1;
        r1.z = A00 * v1.z + A01 * v1.w + b0;  r1.w = A10 * v1.z + A11 * v1.w + b1;
        r2.x = A00 * v2.x + A01 * v2.y + b0;  r2.y = A10 * v2.x + A11 * v2.y + b1;
        r2.z = A00 * v2.z + A01 * v2.w + b0;  r2.w = A10 * v2.z + A11 * v2.w + b1;
        r3.x = A00 * v3.x + A01 * v3.y + b0;  r3.y = A10 * v3.x + A11 * v3.y + b1;
        r3.z = A00 * v3.z + A01 * v3.w + b0;  r3.w = A10 * v3.z + A11 * v3.w + b1;
        __builtin_nontemporal_store(r0, &q[i]);
        __builtin_nontemporal_store(r1, &q[i + 256]);
        __builtin_nontemporal_store(r2, &q[i + 512]);
        __builtin_nontemporal_store(r3, &q[i + 768]);
    }
}

extern "C" void kernel_launch(void* const* d_in, const int* in_sizes, int n_in,
                              void* d_out, int out_size, void* d_ws, size_t ws_size,
                              hipStream_t stream) {
    (void)in_sizes; (void)n_in; (void)out_size; (void)ws_size;
    const float* z     = (const float*)d_in[0];
    const float* gamma = (const float*)d_in[1];
    const float* beta  = (const float*)d_in[2];
    float* out = (float*)d_out;
    float* ws  = (float*)d_ws;   // 2048 planes * 8 floats = 64 KB used

    reduce_kernel<<<PLANES, 256, 0, stream>>>(z, ws);
    apply_kernel<<<PLANES, 256, 0, stream>>>(z, ws, gamma, beta, out);
}